// Round 10
// baseline (651.820 us; speedup 1.0000x reference)
//
#include <hip/hip_runtime.h>
#include <math.h>

#define NN 50000
#define RR 8
#define EE 800000
#define RN 400000            // RR * NN
#define DIN 128
#define K1 1024              // RR * DIN
#define KTOT 1152            // K1 + DIN
#define NBLK 391             // ceil(RN / 1024)
#define LDW 1160             // LDS row width (elems): 1152 + 8 pad, 16B-aligned rows

// ---------------- workspace layout (bytes) ----------------
#define OFF_HB0  0UL           // h bf16: [NN][128] = 12,800,000
#define OFF_HB1  12800000UL    // h bf16: [NN][128] = 12,800,000
#define OFF_XB   25600000UL    // x bf16: [NN][128] = 12,800,000
#define OFF_LG   38400000UL    // logits f32: [NN][64] = 12,800,000
#define OFF_WT   51200000UL    // W^T bf16: 4 x 147456 elems = 1,179,648
#define OFF_OFFS 52379648UL    // offsets: (RN+1) ints -> 1,600,128
#define OFF_CUR  53979776UL    // cursor/hist: RN ints = 1,600,000
#define OFF_SRT  55579776UL    // sorted_src: EE ints = 3,200,000
#define OFF_BS   58779776UL    // block sums = 4,096
#define WS_NEED  58783872UL

typedef short bf16x8 __attribute__((ext_vector_type(8)));
typedef float f32x4 __attribute__((ext_vector_type(4)));

__device__ __forceinline__ unsigned f2bf(float f) {       // RNE f32 -> bf16 bits
    unsigned x = __float_as_uint(f);
    return (x + 0x7fffu + ((x >> 16) & 1u)) >> 16;
}
__device__ __forceinline__ float bflo(unsigned p) { return __uint_as_float(p << 16); }
__device__ __forceinline__ float bfhi(unsigned p) { return __uint_as_float(p & 0xffff0000u); }

// ---------------- one-time converts ----------------
__global__ void k_cvt(const float* __restrict__ x, ushort* __restrict__ xb) {
    int i = blockIdx.x * 256 + threadIdx.x;
    if (i >= NN * 32) return;                 // float4 granules
    float4 v = ((const float4*)x)[i];
    ushort4 o;
    o.x = (ushort)f2bf(v.x); o.y = (ushort)f2bf(v.y);
    o.z = (ushort)f2bf(v.z); o.w = (ushort)f2bf(v.w);
    ((ushort4*)xb)[i] = o;
}

// build W^T[o][k] bf16, k in [0,1152): k<1024 -> W[k>>7][k&127][o], else root[k-1024][o]
__global__ void k_wt(const float* __restrict__ W, const float* __restrict__ Rt,
                     ushort* __restrict__ WT, int O) {
    int o = blockIdx.x;
    for (int k = threadIdx.x; k < KTOT; k += 256) {
        float v = (k < K1)
            ? W[(size_t)(k >> 7) * 128 * O + (size_t)(k & 127) * O + o]
            : Rt[(size_t)(k - K1) * O + o];
        WT[(size_t)o * KTOT + k] = (ushort)f2bf(v);
    }
}

// ---------------- edge preprocessing (counting sort by s = dst*8 + r) ----------------
__global__ void k_hist(const int* __restrict__ ei, const int* __restrict__ et,
                       int* __restrict__ hist) {
    int e = blockIdx.x * blockDim.x + threadIdx.x;
    if (e >= EE) return;
    atomicAdd(&hist[ei[EE + e] * RR + et[e]], 1);
}

__global__ void k_scan1(const int* __restrict__ hist, int* __restrict__ offs,
                        int* __restrict__ bsums) {
    __shared__ int tmp[1024];
    int tid = threadIdx.x;
    int g = blockIdx.x * 1024 + tid;
    int v = (g < RN) ? hist[g] : 0;
    tmp[tid] = v;
    __syncthreads();
    for (int off = 1; off < 1024; off <<= 1) {
        int t = tmp[tid];
        if (tid >= off) t += tmp[tid - off];
        __syncthreads();
        tmp[tid] = t;
        __syncthreads();
    }
    if (g < RN) offs[g] = tmp[tid] - v;
    if (tid == 1023) bsums[blockIdx.x] = tmp[1023];
}

__global__ void k_scan2(int* __restrict__ bsums) {
    __shared__ int tmp[1024];
    int tid = threadIdx.x;
    int v = (tid < NBLK) ? bsums[tid] : 0;
    tmp[tid] = v;
    __syncthreads();
    for (int off = 1; off < 1024; off <<= 1) {
        int t = tmp[tid];
        if (tid >= off) t += tmp[tid - off];
        __syncthreads();
        tmp[tid] = t;
        __syncthreads();
    }
    if (tid < NBLK) bsums[tid] = tmp[tid] - v;
}

__global__ void k_scan3(int* __restrict__ offs, const int* __restrict__ bsums) {
    int g = blockIdx.x * 1024 + threadIdx.x;
    if (g < RN) offs[g] += bsums[blockIdx.x];
    else if (g == RN) offs[RN] = EE;
}

__global__ void k_scatter(const int* __restrict__ ei, const int* __restrict__ et,
                          const int* __restrict__ offs, int* __restrict__ cur,
                          int* __restrict__ ssrc) {
    int e = blockIdx.x * blockDim.x + threadIdx.x;
    if (e >= EE) return;
    int s = ei[EE + e] * RR + et[e];
    ssrc[offs[s] + atomicAdd(&cur[s], 1)] = ei[e];
}

// ---------------- fused layer: agg -> LDS -> MFMA, one barrier ----------------
// Block = 16 nodes, 512 threads (8 waves); 3125 blocks; 4 blocks/CU (37KB LDS)
// = 32 waves/CU full occupancy. Phase 1: wave w aggregates nodes 2w,2w+1 (all
// 8 relations; k_agg's proven shfl-safe inner loop) straight into LDS bf16
// A-tile As[16][LDW]; 16B chunks XOR-swizzled (c ^= nl, both sides); root row
// cols [1024,1152) copied cooperatively. ONE barrier. Phase 2: wave w does
// output cols [16w,16w+16): 36 MFMA vs L2-resident WT. No u round-trip
// (R5-R9: split structure floor was 125us/layer, >70% of it u-latency).
template<int O, bool RELU, bool OUTF32>
__global__ __launch_bounds__(512) void k_fused(
        const ushort* __restrict__ hb, const int* __restrict__ offs,
        const int* __restrict__ ssrc, const ushort* __restrict__ WT,
        const float* __restrict__ bias, void* __restrict__ outv) {
    __shared__ ushort As[16][LDW];
    const int tid = threadIdx.x;
    const int lane = tid & 63;
    const int w = tid >> 6;                  // 0..7
    const int half = lane >> 5;
    const int sub = lane & 31;
    const int nbase = blockIdx.x * 16;
    const uint2* h4 = (const uint2*)hb;

    // ---- phase 1: gather/aggregate 2 nodes per wave
    for (int i = 0; i < 2; ++i) {            // uniform
        int nl = w * 2 + i;
        int n = nbase + nl;
        int b = offs[n * 8 + min(lane, 8)];
        int b0 = __shfl(b, 0), b8 = __shfl(b, 8);
        int nb = b8 - b0;
        int sv = ssrc[min(b0 + min(lane, max(nb - 1, 0)), EE - 1)];
#pragma unroll
        for (int t = 0; t < 4; ++t) {
            int r = 2 * t + half;
            int beg = __shfl(b, r);
            int end = __shfl(b, r + 1);
            int len = end - beg;
            int mx = max(__shfl(len, 0), __shfl(len, 32));  // wave-uniform
            float a0 = 0.f, a1 = 0.f, a2 = 0.f, a3 = 0.f;
            for (int j = 0; j < mx; j += 2) {   // uniform trip: full exec
                int l0 = beg - b0 + j;
                int l1 = l0 + 1;
                int s0 = __shfl(sv, min(l0, 63));
                int s1 = __shfl(sv, min(l1, 63));
                if (l1 >= 64) {                 // rare: node degree > 64
                    s0 = ssrc[min(b0 + l0, EE - 1)];
                    s1 = ssrc[min(b0 + l1, EE - 1)];
                }
                uint2 q0 = h4[(size_t)s0 * 32 + sub];
                uint2 q1 = h4[(size_t)s1 * 32 + sub];
                if (j < len) {
                    a0 += bflo(q0.x); a1 += bfhi(q0.x);
                    a2 += bflo(q0.y); a3 += bfhi(q0.y);
                }
                if (j + 1 < len) {
                    a0 += bflo(q1.x); a1 += bfhi(q1.x);
                    a2 += bflo(q1.y); a3 += bfhi(q1.y);
                }
            }
            float inv = 1.0f / (float)max(len, 1);
            uint2 wv;
            wv.x = f2bf(a0 * inv) | (f2bf(a1 * inv) << 16);
            wv.y = f2bf(a2 * inv) | (f2bf(a3 * inv) << 16);
            // elem col = r*128 + sub*4; 16B chunk c = r*16 + (sub>>1); swizzle c^nl
            int c = r * 16 + (sub >> 1);
            *(uint2*)(&As[nl][((c ^ nl) << 3) + (sub & 1) * 4]) = wv;
        }
    }
    // ---- root row copy: cols [1024,1152), chunks c in [128,144)
    {
        int row = tid >> 5, s2 = tid & 31;
        uint2 q = h4[(size_t)(nbase + row) * 32 + s2];
        int c = 128 + (s2 >> 1);
        *(uint2*)(&As[row][((c ^ row) << 3) + (s2 & 1) * 4]) = q;
    }
    __syncthreads();
    // ---- phase 2: MFMA. wave w -> cols [16w, 16w+16)
    if (w * 16 < O) {
        const int lr = lane & 15, hi = lane >> 4;
        f32x4 acc = {};
        const ushort* wcol = WT + (size_t)(w * 16 + lr) * KTOT + hi * 8;
#pragma unroll
        for (int ks = 0; ks < 36; ++ks) {
            int g = ks * 4 + hi;             // 16B chunk index in row lr
            bf16x8 a = *(const bf16x8*)(&As[lr][(g ^ lr) << 3]);
            bf16x8 bb = *(const bf16x8*)(wcol + ks * 32);
            acc = __builtin_amdgcn_mfma_f32_16x16x32_bf16(a, bb, acc, 0, 0, 0);
        }
        int col = w * 16 + lr;
        float bs = bias[col];
#pragma unroll
        for (int j = 0; j < 4; ++j) {
            int row = nbase + hi * 4 + j;    // C/D: col=lane&15, row=(lane>>4)*4+j
            float v = acc[j] + bs;
            if (RELU) v = fmaxf(v, 0.f);
            if (OUTF32) ((float*)outv)[(size_t)row * O + col] = v;
            else ((ushort*)outv)[(size_t)row * O + col] = (ushort)f2bf(v);
        }
    }
}

// ---------------- final log_softmax over 64 cols ----------------
__global__ void k_logsoftmax(const float* __restrict__ in, float* __restrict__ out) {
    int row = blockIdx.x * 4 + (threadIdx.x >> 6);
    int lane = threadIdx.x & 63;
    if (row >= NN) return;
    float v = in[(size_t)row * 64 + lane];
    float m = v;
#pragma unroll
    for (int off = 32; off; off >>= 1) m = fmaxf(m, __shfl_xor(m, off, 64));
    float e = expf(v - m);
    float s = e;
#pragma unroll
    for (int off = 32; off; off >>= 1) s += __shfl_xor(s, off, 64);
    out[(size_t)row * 64 + lane] = v - m - logf(s);
}

extern "C" void kernel_launch(void* const* d_in, const int* in_sizes, int n_in,
                              void* d_out, int out_size, void* d_ws, size_t ws_size,
                              hipStream_t stream) {
    const float* x  = (const float*)d_in[0];
    const int*   ei = (const int*)d_in[1];
    const int*   et = (const int*)d_in[2];
    const float* W[4]    = {(const float*)d_in[3], (const float*)d_in[6],
                            (const float*)d_in[9], (const float*)d_in[12]};
    const float* root[4] = {(const float*)d_in[4], (const float*)d_in[7],
                            (const float*)d_in[10], (const float*)d_in[13]};
    const float* bias[4] = {(const float*)d_in[5], (const float*)d_in[8],
                            (const float*)d_in[11], (const float*)d_in[14]};

    if (ws_size < WS_NEED) return;

    char* ws = (char*)d_ws;
    ushort* hb0  = (ushort*)(ws + OFF_HB0);
    ushort* hb1  = (ushort*)(ws + OFF_HB1);
    ushort* xb   = (ushort*)(ws + OFF_XB);
    float*  lg   = (float*)(ws + OFF_LG);
    ushort* WT   = (ushort*)(ws + OFF_WT);
    int*   offs  = (int*)(ws + OFF_OFFS);
    int*   cur   = (int*)(ws + OFF_CUR);
    int*   ssrc  = (int*)(ws + OFF_SRT);
    int*   bsums = (int*)(ws + OFF_BS);
    ushort* WTl[4] = {WT, WT + 147456, WT + 2 * 147456, WT + 3 * 147456};

    // one-time converts
    k_cvt<<<(NN * 32 + 255) / 256, 256, 0, stream>>>(x, xb);
    k_wt<<<128, 256, 0, stream>>>(W[0], root[0], WTl[0], 128);
    k_wt<<<128, 256, 0, stream>>>(W[1], root[1], WTl[1], 128);
    k_wt<<<128, 256, 0, stream>>>(W[2], root[2], WTl[2], 128);
    k_wt<<<64,  256, 0, stream>>>(W[3], root[3], WTl[3], 64);

    // edge sort by segment key s = dst*8 + etype
    hipMemsetAsync(cur, 0, RN * sizeof(int), stream);
    k_hist<<<(EE + 255) / 256, 256, 0, stream>>>(ei, et, cur);
    k_scan1<<<NBLK, 1024, 0, stream>>>(cur, offs, bsums);
    k_scan2<<<1, 1024, 0, stream>>>(bsums);
    k_scan3<<<NBLK, 1024, 0, stream>>>(offs, bsums);
    hipMemsetAsync(cur, 0, RN * sizeof(int), stream);
    k_scatter<<<(EE + 255) / 256, 256, 0, stream>>>(ei, et, offs, cur, ssrc);

    const int G = NN / 16;   // 3125 (exact)
    k_fused<128, true,  false><<<G, 512, 0, stream>>>(xb,  offs, ssrc, WTl[0], bias[0], hb0);
    k_fused<128, true,  false><<<G, 512, 0, stream>>>(hb0, offs, ssrc, WTl[1], bias[1], hb1);
    k_fused<128, true,  false><<<G, 512, 0, stream>>>(hb1, offs, ssrc, WTl[2], bias[2], hb0);
    k_fused<64,  false, true ><<<G, 512, 0, stream>>>(hb0, offs, ssrc, WTl[3], bias[3], lg);
    k_logsoftmax<<<(NN + 3) / 4, 256, 0, stream>>>(lg, (float*)d_out);
}

// Round 11
// 572.180 us; speedup vs baseline: 1.1392x; 1.1392x over previous
//
#include <hip/hip_runtime.h>
#include <math.h>

#define NN 50000
#define RR 8
#define EE 800000
#define RN 400000            // RR * NN
#define DIN 128
#define K1 1024              // RR * DIN
#define KTOT 1152            // K1 + DIN
#define NBLK 391             // ceil(RN / 1024)
#define LDW 1160             // LDS row width (elems) = 145 16B-chunks (ODD -> natural
                             // per-row bank rotation; NO XOR swizzle — R10 post-mortem)

// ---------------- workspace layout (bytes) ----------------
#define OFF_HB0  0UL           // h bf16: [NN][128] = 12,800,000
#define OFF_HB1  12800000UL    // h bf16: [NN][128] = 12,800,000
#define OFF_XB   25600000UL    // x bf16: [NN][128] = 12,800,000
#define OFF_LG   38400000UL    // logits f32: [NN][64] = 12,800,000
#define OFF_WT   51200000UL    // W^T bf16: 4 x 147456 elems = 1,179,648
#define OFF_OFFS 52379648UL    // offsets: (RN+1) ints -> 1,600,128
#define OFF_CUR  53979776UL    // cursor/hist: RN ints = 1,600,000
#define OFF_SRT  55579776UL    // sorted_src: EE ints = 3,200,000
#define OFF_BS   58779776UL    // block sums = 4,096
#define WS_NEED  58783872UL

typedef short bf16x8 __attribute__((ext_vector_type(8)));
typedef float f32x4 __attribute__((ext_vector_type(4)));

__device__ __forceinline__ unsigned f2bf(float f) {       // RNE f32 -> bf16 bits
    unsigned x = __float_as_uint(f);
    return (x + 0x7fffu + ((x >> 16) & 1u)) >> 16;
}
__device__ __forceinline__ float bflo(unsigned p) { return __uint_as_float(p << 16); }
__device__ __forceinline__ float bfhi(unsigned p) { return __uint_as_float(p & 0xffff0000u); }

// ---------------- one-time converts ----------------
__global__ void k_cvt(const float* __restrict__ x, ushort* __restrict__ xb) {
    int i = blockIdx.x * 256 + threadIdx.x;
    if (i >= NN * 32) return;                 // float4 granules
    float4 v = ((const float4*)x)[i];
    ushort4 o;
    o.x = (ushort)f2bf(v.x); o.y = (ushort)f2bf(v.y);
    o.z = (ushort)f2bf(v.z); o.w = (ushort)f2bf(v.w);
    ((ushort4*)xb)[i] = o;
}

// build W^T[o][k] bf16, k in [0,1152): k<1024 -> W[k>>7][k&127][o], else root[k-1024][o]
__global__ void k_wt(const float* __restrict__ W, const float* __restrict__ Rt,
                     ushort* __restrict__ WT, int O) {
    int o = blockIdx.x;
    for (int k = threadIdx.x; k < KTOT; k += 256) {
        float v = (k < K1)
            ? W[(size_t)(k >> 7) * 128 * O + (size_t)(k & 127) * O + o]
            : Rt[(size_t)(k - K1) * O + o];
        WT[(size_t)o * KTOT + k] = (ushort)f2bf(v);
    }
}

// ---------------- edge preprocessing (counting sort by s = dst*8 + r) ----------------
__global__ void k_hist(const int* __restrict__ ei, const int* __restrict__ et,
                       int* __restrict__ hist) {
    int e = blockIdx.x * blockDim.x + threadIdx.x;
    if (e >= EE) return;
    atomicAdd(&hist[ei[EE + e] * RR + et[e]], 1);
}

__global__ void k_scan1(const int* __restrict__ hist, int* __restrict__ offs,
                        int* __restrict__ bsums) {
    __shared__ int tmp[1024];
    int tid = threadIdx.x;
    int g = blockIdx.x * 1024 + tid;
    int v = (g < RN) ? hist[g] : 0;
    tmp[tid] = v;
    __syncthreads();
    for (int off = 1; off < 1024; off <<= 1) {
        int t = tmp[tid];
        if (tid >= off) t += tmp[tid - off];
        __syncthreads();
        tmp[tid] = t;
        __syncthreads();
    }
    if (g < RN) offs[g] = tmp[tid] - v;
    if (tid == 1023) bsums[blockIdx.x] = tmp[1023];
}

__global__ void k_scan2(int* __restrict__ bsums) {
    __shared__ int tmp[1024];
    int tid = threadIdx.x;
    int v = (tid < NBLK) ? bsums[tid] : 0;
    tmp[tid] = v;
    __syncthreads();
    for (int off = 1; off < 1024; off <<= 1) {
        int t = tmp[tid];
        if (tid >= off) t += tmp[tid - off];
        __syncthreads();
        tmp[tid] = t;
        __syncthreads();
    }
    if (tid < NBLK) bsums[tid] = tmp[tid] - v;
}

__global__ void k_scan3(int* __restrict__ offs, const int* __restrict__ bsums) {
    int g = blockIdx.x * 1024 + threadIdx.x;
    if (g < RN) offs[g] += bsums[blockIdx.x];
    else if (g == RN) offs[RN] = EE;
}

__global__ void k_scatter(const int* __restrict__ ei, const int* __restrict__ et,
                          const int* __restrict__ offs, int* __restrict__ cur,
                          int* __restrict__ ssrc) {
    int e = blockIdx.x * blockDim.x + threadIdx.x;
    if (e >= EE) return;
    int s = ei[EE + e] * RR + et[e];
    ssrc[offs[s] + atomicAdd(&cur[s], 1)] = ei[e];
}

// ---------------- fused layer: agg -> LDS -> MFMA, one barrier ----------------
// Block = 32 nodes, 512 threads (8 waves); 1563 blocks; 74KB LDS -> 2 blocks/CU.
// Phase 1: wave w aggregates nodes 4w..4w+3. Per node: quarter-wave (16 lanes x
// uint4 = full 256B row) per relation, 4 relations concurrently x 2 passes,
// 2-deep edge unroll = 8 rows in flight/wave. shfl-safety: all shfls at full
// exec (uniform trip = max over quarters, clamped indices); per-lane validity
// only guards VALU accumulates. Phase 2: 36 MFMA per wave against L2-resident
// WT; A from LDS (stride-145 chunks -> conflict-free b128, no XOR).
template<int O, bool RELU, bool OUTF32>
__global__ __launch_bounds__(512) void k_fused(
        const ushort* __restrict__ hb, const int* __restrict__ offs,
        const int* __restrict__ ssrc, const ushort* __restrict__ WT,
        const float* __restrict__ bias, void* __restrict__ outv) {
    __shared__ ushort As[32 * LDW];
    const int tid = threadIdx.x;
    const int lane = tid & 63;
    const int w = tid >> 6;                  // 0..7
    const int q = lane >> 4;                 // quarter 0..3 = relation slot
    const int ll = lane & 15;                // 16B chunk within row
    const int nbase = blockIdx.x * 32;
    const uint4* h16 = (const uint4*)hb;     // h row = 16 uint4

    // ---- phase 1: gather/aggregate 4 nodes per wave
    for (int i = 0; i < 4; ++i) {            // wave-uniform
        int nl = w * 4 + i;
        int n = min(nbase + nl, NN - 1);     // clamp tail (junk rows masked later)
        int b = offs[n * 8 + min(lane, 8)];
        int b0 = __shfl(b, 0), b8 = __shfl(b, 8);
        int nb = b8 - b0;
        int sv = ssrc[min(b0 + min(lane, max(nb - 1, 0)), EE - 1)];
#pragma unroll
        for (int p = 0; p < 2; ++p) {        // relation pass: r = p*4 + q
            int r = p * 4 + q;
            int beg = __shfl(b, r);          // full exec, per-lane index ok
            int end = __shfl(b, r + 1);
            int len = end - beg;
            int mx = max(max(__shfl(len, 0), __shfl(len, 16)),
                         max(__shfl(len, 32), __shfl(len, 48)));  // wave-uniform
            int begl = beg - b0;
            float a0 = 0.f, a1 = 0.f, a2 = 0.f, a3 = 0.f;
            float a4 = 0.f, a5 = 0.f, a6 = 0.f, a7 = 0.f;
            for (int j = 0; j < mx; j += 2) {   // uniform trip: full exec
                int e0 = begl + j, e1 = e0 + 1;
                int s0 = __shfl(sv, min(e0, 63));
                int s1 = __shfl(sv, min(e1, 63));
                if (e1 >= 64) {                 // rare: node degree > 64
                    s0 = ssrc[min(b0 + e0, EE - 1)];
                    s1 = ssrc[min(b0 + e1, EE - 1)];
                }
                uint4 u0 = h16[(size_t)s0 * 16 + ll];
                uint4 u1 = h16[(size_t)s1 * 16 + ll];
                if (j < len) {
                    a0 += bflo(u0.x); a1 += bfhi(u0.x);
                    a2 += bflo(u0.y); a3 += bfhi(u0.y);
                    a4 += bflo(u0.z); a5 += bfhi(u0.z);
                    a6 += bflo(u0.w); a7 += bfhi(u0.w);
                }
                if (j + 1 < len) {
                    a0 += bflo(u1.x); a1 += bfhi(u1.x);
                    a2 += bflo(u1.y); a3 += bfhi(u1.y);
                    a4 += bflo(u1.z); a5 += bfhi(u1.z);
                    a6 += bflo(u1.w); a7 += bfhi(u1.w);
                }
            }
            float inv = 1.0f / (float)max(len, 1);
            uint4 o;
            o.x = f2bf(a0 * inv) | (f2bf(a1 * inv) << 16);
            o.y = f2bf(a2 * inv) | (f2bf(a3 * inv) << 16);
            o.z = f2bf(a4 * inv) | (f2bf(a5 * inv) << 16);
            o.w = f2bf(a6 * inv) | (f2bf(a7 * inv) << 16);
            *(uint4*)(&As[nl * LDW + (r * 16 + ll) * 8]) = o;
        }
    }
    // ---- root rows: cols [1024,1152) = chunks [128,144); 512 thr x 16B = all 32 rows
    {
        int row = tid >> 4;                  // 0..31
        int cc = tid & 15;
        uint4 v = h16[(size_t)min(nbase + row, NN - 1) * 16 + cc];
        *(uint4*)(&As[row * LDW + (128 + cc) * 8]) = v;
    }
    __syncthreads();
    // ---- phase 2: MFMA. task split: O=128 -> wave w: cols 16w, m-subtiles 0,1;
    //      O=64 -> wave w: cols 16*(w&3), m-subtile w>>2.
    constexpr int NTILE = O / 16;
    const int cw = w % NTILE;
    const int mt0 = (NTILE == 8) ? 0 : (w / NTILE);
    constexpr int NMT = (NTILE == 8) ? 2 : 1;
    const int lr = lane & 15, hi = lane >> 4;
    f32x4 acc[NMT] = {};
    const ushort* wcol = WT + (size_t)(cw * 16 + lr) * KTOT + hi * 8;
#pragma unroll
    for (int ks = 0; ks < 36; ++ks) {
        bf16x8 bb = *(const bf16x8*)(wcol + ks * 32);
        int g = ks * 4 + hi;
#pragma unroll
        for (int m = 0; m < NMT; ++m) {
            int row = (mt0 + m) * 16 + lr;
            bf16x8 a = *(const bf16x8*)(&As[row * LDW + g * 8]);
            acc[m] = __builtin_amdgcn_mfma_f32_16x16x32_bf16(a, bb, acc[m], 0, 0, 0);
        }
    }
    int col = cw * 16 + lr;
    float bs = bias[col];
#pragma unroll
    for (int m = 0; m < NMT; ++m) {
#pragma unroll
        for (int j = 0; j < 4; ++j) {        // C/D: col=lane&15, row=(lane>>4)*4+j
            int row = nbase + (mt0 + m) * 16 + hi * 4 + j;
            if (row >= NN) continue;
            float v = acc[m][j] + bs;
            if (RELU) v = fmaxf(v, 0.f);
            if (OUTF32) ((float*)outv)[(size_t)row * O + col] = v;
            else ((ushort*)outv)[(size_t)row * O + col] = (ushort)f2bf(v);
        }
    }
}

// ---------------- final log_softmax over 64 cols ----------------
__global__ void k_logsoftmax(const float* __restrict__ in, float* __restrict__ out) {
    int row = blockIdx.x * 4 + (threadIdx.x >> 6);
    int lane = threadIdx.x & 63;
    if (row >= NN) return;
    float v = in[(size_t)row * 64 + lane];
    float m = v;
#pragma unroll
    for (int off = 32; off; off >>= 1) m = fmaxf(m, __shfl_xor(m, off, 64));
    float e = expf(v - m);
    float s = e;
#pragma unroll
    for (int off = 32; off; off >>= 1) s += __shfl_xor(s, off, 64);
    out[(size_t)row * 64 + lane] = v - m - logf(s);
}

extern "C" void kernel_launch(void* const* d_in, const int* in_sizes, int n_in,
                              void* d_out, int out_size, void* d_ws, size_t ws_size,
                              hipStream_t stream) {
    const float* x  = (const float*)d_in[0];
    const int*   ei = (const int*)d_in[1];
    const int*   et = (const int*)d_in[2];
    const float* W[4]    = {(const float*)d_in[3], (const float*)d_in[6],
                            (const float*)d_in[9], (const float*)d_in[12]};
    const float* root[4] = {(const float*)d_in[4], (const float*)d_in[7],
                            (const float*)d_in[10], (const float*)d_in[13]};
    const float* bias[4] = {(const float*)d_in[5], (const float*)d_in[8],
                            (const float*)d_in[11], (const float*)d_in[14]};

    if (ws_size < WS_NEED) return;

    char* ws = (char*)d_ws;
    ushort* hb0  = (ushort*)(ws + OFF_HB0);
    ushort* hb1  = (ushort*)(ws + OFF_HB1);
    ushort* xb   = (ushort*)(ws + OFF_XB);
    float*  lg   = (float*)(ws + OFF_LG);
    ushort* WT   = (ushort*)(ws + OFF_WT);
    int*   offs  = (int*)(ws + OFF_OFFS);
    int*   cur   = (int*)(ws + OFF_CUR);
    int*   ssrc  = (int*)(ws + OFF_SRT);
    int*   bsums = (int*)(ws + OFF_BS);
    ushort* WTl[4] = {WT, WT + 147456, WT + 2 * 147456, WT + 3 * 147456};

    // one-time converts
    k_cvt<<<(NN * 32 + 255) / 256, 256, 0, stream>>>(x, xb);
    k_wt<<<128, 256, 0, stream>>>(W[0], root[0], WTl[0], 128);
    k_wt<<<128, 256, 0, stream>>>(W[1], root[1], WTl[1], 128);
    k_wt<<<128, 256, 0, stream>>>(W[2], root[2], WTl[2], 128);
    k_wt<<<64,  256, 0, stream>>>(W[3], root[3], WTl[3], 64);

    // edge sort by segment key s = dst*8 + etype
    hipMemsetAsync(cur, 0, RN * sizeof(int), stream);
    k_hist<<<(EE + 255) / 256, 256, 0, stream>>>(ei, et, cur);
    k_scan1<<<NBLK, 1024, 0, stream>>>(cur, offs, bsums);
    k_scan2<<<1, 1024, 0, stream>>>(bsums);
    k_scan3<<<NBLK, 1024, 0, stream>>>(offs, bsums);
    hipMemsetAsync(cur, 0, RN * sizeof(int), stream);
    k_scatter<<<(EE + 255) / 256, 256, 0, stream>>>(ei, et, offs, cur, ssrc);

    const int G = (NN + 31) / 32;   // 1563
    k_fused<128, true,  false><<<G, 512, 0, stream>>>(xb,  offs, ssrc, WTl[0], bias[0], hb0);
    k_fused<128, true,  false><<<G, 512, 0, stream>>>(hb0, offs, ssrc, WTl[1], bias[1], hb1);
    k_fused<128, true,  false><<<G, 512, 0, stream>>>(hb1, offs, ssrc, WTl[2], bias[2], hb0);
    k_fused<64,  false, true ><<<G, 512, 0, stream>>>(hb0, offs, ssrc, WTl[3], bias[3], lg);
    k_logsoftmax<<<(NN + 3) / 4, 256, 0, stream>>>(lg, (float*)d_out);
}